// Round 1
// baseline (144.470 us; speedup 1.0000x reference)
//
#include <hip/hip_runtime.h>
#include <hip/hip_bf16.h>

#define BDIM 8192
#define DDIM 256
#define BM 128
#define BN 128
#define BK 64
#define LDS_STRIDE 72  // BK + 8 pad (144 B) — breaks power-of-2 bank aliasing

#define MARGIN1 5.0f
#define MARGIN2 10.0f
// n_pairs = 8192*8191/2 = 33550336
#define INV_NPAIRS (1.0f / 33550336.0f)

typedef __attribute__((ext_vector_type(4))) float  f32x4;
typedef __attribute__((ext_vector_type(4))) __bf16 bf16x4;
typedef __attribute__((ext_vector_type(8))) __bf16 bf16x8;

// One wave per row: convert fp32 -> bf16 (RNE), compute sq[i] from the
// ROUNDED values so d2 = |Fb_i - Fb_j|^2 is exactly consistent (>= 0).
__global__ __launch_bounds__(256) void prep_kernel(
    const float* __restrict__ F, __bf16* __restrict__ Fb,
    float* __restrict__ sq, float* __restrict__ out)
{
    if (blockIdx.x == 0 && threadIdx.x == 0) *out = 0.0f;  // all prep blocks retire before main kernel
    const int row  = blockIdx.x * 4 + (threadIdx.x >> 6);
    const int lane = threadIdx.x & 63;
    f32x4 v = *reinterpret_cast<const f32x4*>(F + (size_t)row * DDIM + lane * 4);
    bf16x4 b;
    b.x = (__bf16)v.x; b.y = (__bf16)v.y; b.z = (__bf16)v.z; b.w = (__bf16)v.w;
    *reinterpret_cast<bf16x4*>(Fb + (size_t)row * DDIM + lane * 4) = b;
    float f0 = (float)b.x, f1 = (float)b.y, f2 = (float)b.z, f3 = (float)b.w;
    float s = f0 * f0 + f1 * f1 + f2 * f2 + f3 * f3;
    #pragma unroll
    for (int off = 32; off > 0; off >>= 1) s += __shfl_xor(s, off, 64);
    if (lane == 0) sq[row] = s;
}

// 128x128 tile of the Gram matrix per block; 4 waves in 2x2, each wave a
// 64x64 subtile = 4x4 grid of mfma_f32_16x16x32_bf16. Fused distance/margin
// epilogue + masked block reduction.
__global__ __launch_bounds__(256) void pair_loss_kernel(
    const __bf16* __restrict__ Fb, const float* __restrict__ sq,
    const int* __restrict__ labels, const int* __restrict__ mlabels,
    float* __restrict__ out)
{
    const int ti = blockIdx.x, tj = blockIdx.y;
    if (tj < ti) return;  // only upper-triangle tile blocks do work

    __shared__ __bf16 As[BM * LDS_STRIDE];
    __shared__ __bf16 Bs[BN * LDS_STRIDE];
    __shared__ float red[4];

    const int tid  = threadIdx.x;
    const int lane = tid & 63;
    const int wid  = tid >> 6;
    const int wm   = wid >> 1;   // 0..1
    const int wn   = wid & 1;    // 0..1

    const int i0 = ti * BM;
    const int j0 = tj * BN;

    f32x4 acc[4][4];
    #pragma unroll
    for (int a = 0; a < 4; a++)
        #pragma unroll
        for (int b = 0; b < 4; b++)
            acc[a][b] = (f32x4){0.f, 0.f, 0.f, 0.f};

    #pragma unroll 1
    for (int k0 = 0; k0 < DDIM; k0 += BK) {
        // Stage A (rows i0..i0+127) and B (rows j0..j0+127), K-slice [k0,k0+64).
        // 128 rows x 8 chunks of 16 B per tile; each thread moves 4 chunks of each.
        #pragma unroll
        for (int it = 0; it < 4; it++) {
            int c  = tid + it * 256;
            int r  = c >> 3;
            int cc = c & 7;
            *reinterpret_cast<bf16x8*>(&As[r * LDS_STRIDE + cc * 8]) =
                *reinterpret_cast<const bf16x8*>(&Fb[(size_t)(i0 + r) * DDIM + k0 + cc * 8]);
            *reinterpret_cast<bf16x8*>(&Bs[r * LDS_STRIDE + cc * 8]) =
                *reinterpret_cast<const bf16x8*>(&Fb[(size_t)(j0 + r) * DDIM + k0 + cc * 8]);
        }
        __syncthreads();

        #pragma unroll
        for (int ks = 0; ks < 2; ks++) {
            bf16x8 afrag[4], bfrag[4];
            const int koff = ks * 32 + (lane >> 4) * 8;  // A/B operand: k = quad*8 + j
            const int ra   = wm * 64 + (lane & 15);      // m = lane & 15
            const int rb   = wn * 64 + (lane & 15);      // n = lane & 15
            #pragma unroll
            for (int t = 0; t < 4; t++)
                afrag[t] = *reinterpret_cast<const bf16x8*>(&As[(ra + t * 16) * LDS_STRIDE + koff]);
            #pragma unroll
            for (int t = 0; t < 4; t++)
                bfrag[t] = *reinterpret_cast<const bf16x8*>(&Bs[(rb + t * 16) * LDS_STRIDE + koff]);
            #pragma unroll
            for (int tm = 0; tm < 4; tm++)
                #pragma unroll
                for (int tn = 0; tn < 4; tn++)
                    acc[tm][tn] = __builtin_amdgcn_mfma_f32_16x16x32_bf16(
                        afrag[tm], bfrag[tn], acc[tm][tn], 0, 0, 0);
        }
        __syncthreads();
    }

    // Epilogue. C/D layout (m89-verified): col = lane&15, row = (lane>>4)*4 + reg.
    const int coll = lane & 15;
    const int rowq = (lane >> 4) * 4;
    float lsum = 0.0f;

    float sjv[4]; int ljv[4], mjv[4], jv[4];
    #pragma unroll
    for (int tn = 0; tn < 4; tn++) {
        int j = j0 + wn * 64 + tn * 16 + coll;
        jv[tn] = j; sjv[tn] = sq[j]; ljv[tn] = labels[j]; mjv[tn] = mlabels[j];
    }

    #pragma unroll
    for (int tm = 0; tm < 4; tm++) {
        #pragma unroll
        for (int r = 0; r < 4; r++) {
            const int i = i0 + wm * 64 + tm * 16 + rowq + r;
            const float si = sq[i];
            const int   li = labels[i];
            const int   mi = mlabels[i];
            #pragma unroll
            for (int tn = 0; tn < 4; tn++) {
                const int j = jv[tn];
                if (i < j) {
                    float g    = acc[tm][tn][r];
                    float d2   = fmaxf(si + sjv[tn] - 2.0f * g, 0.0f);
                    float dist = sqrtf(d2);
                    float term;
                    if (li == ljv[tn]) {
                        term = dist;
                    } else {
                        float m = (mi == mjv[tn]) ? MARGIN1 : MARGIN2;
                        term = fmaxf(m - dist, 0.0f);
                    }
                    lsum += term;
                }
            }
        }
    }

    #pragma unroll
    for (int off = 32; off > 0; off >>= 1) lsum += __shfl_xor(lsum, off, 64);
    if (lane == 0) red[wid] = lsum;
    __syncthreads();
    if (tid == 0) atomicAdd(out, (red[0] + red[1] + red[2] + red[3]) * INV_NPAIRS);
}

extern "C" void kernel_launch(void* const* d_in, const int* in_sizes, int n_in,
                              void* d_out, int out_size, void* d_ws, size_t ws_size,
                              hipStream_t stream) {
    const float* F       = (const float*)d_in[0];
    const int*   labels  = (const int*)d_in[1];
    const int*   mlabels = (const int*)d_in[2];
    float*       out     = (float*)d_out;

    __bf16* Fb = (__bf16*)d_ws;                                        // 8192*256*2 = 4 MiB
    float*  sq = (float*)((char*)d_ws + (size_t)BDIM * DDIM * 2);      // + 32 KiB

    prep_kernel<<<BDIM / 4, 256, 0, stream>>>(F, Fb, sq, out);

    dim3 grid(BDIM / BM, BDIM / BN);
    pair_loss_kernel<<<grid, 256, 0, stream>>>(Fb, sq, labels, mlabels, out);
}

// Round 2
// 100.323 us; speedup vs baseline: 1.4400x; 1.4400x over previous
//
#include <hip/hip_runtime.h>
#include <hip/hip_bf16.h>

#define BDIM 8192
#define DDIM 256
#define NT 64                 // 8192/128 tiles per dim
#define NBLK 2080             // NT*(NT+1)/2 upper-triangle tiles
#define MARGIN1 5.0f
#define MARGIN2 10.0f
#define INV_NPAIRS (1.0f / 33550336.0f)   // 8192*8191/2

typedef __attribute__((ext_vector_type(4))) float  f32x4;
typedef __attribute__((ext_vector_type(4))) __bf16 bf16x4;
typedef __attribute__((ext_vector_type(8))) __bf16 bf16x8;

__device__ inline void gload_lds16(const void* g, void* s) {
    __builtin_amdgcn_global_load_lds(
        (const __attribute__((address_space(1))) void*)g,
        (__attribute__((address_space(3))) void*)s, 16, 0, 0);
}

// One wave per row: fp32 -> bf16 (RNE), sq from ROUNDED values (so
// d2 = |Fb_i - Fb_j|^2 is mathematically >= 0), pack {sq, label*2+method}.
__global__ __launch_bounds__(256) void prep_kernel(
    const float* __restrict__ F, const int* __restrict__ labels,
    const int* __restrict__ mlabels, __bf16* __restrict__ Fb,
    float2* __restrict__ meta)
{
    const int row  = blockIdx.x * 4 + (threadIdx.x >> 6);
    const int lane = threadIdx.x & 63;
    f32x4 v = *reinterpret_cast<const f32x4*>(F + (size_t)row * DDIM + lane * 4);
    bf16x4 b;
    b.x = (__bf16)v.x; b.y = (__bf16)v.y; b.z = (__bf16)v.z; b.w = (__bf16)v.w;
    *reinterpret_cast<bf16x4*>(Fb + (size_t)row * DDIM + lane * 4) = b;
    float f0 = (float)b.x, f1 = (float)b.y, f2 = (float)b.z, f3 = (float)b.w;
    float s = f0 * f0 + f1 * f1 + f2 * f2 + f3 * f3;
    #pragma unroll
    for (int off = 32; off > 0; off >>= 1) s += __shfl_xor(s, off, 64);
    if (lane == 0)
        meta[row] = make_float2(s, __int_as_float(labels[row] * 2 + mlabels[row]));
}

#define FT(t) ((t) * (129 - (t)) / 2)   // first linear id of tile-row t

// 128x128 Gram tile per block; XOR-swizzled LDS fed by global_load_lds;
// fused distance/margin epilogue; per-block partial (no atomics).
__global__ __launch_bounds__(256) void pair_loss_kernel(
    const __bf16* __restrict__ Fb, const float2* __restrict__ meta,
    float* __restrict__ partial)
{
    // linear block id -> upper-triangle (ti, tj)
    const int L = blockIdx.x;
    int ti = (int)((129.0f - sqrtf(16641.0f - 8.0f * (float)L)) * 0.5f);
    while (FT(ti + 1) <= L) ++ti;
    while (FT(ti) > L) --ti;
    const int tj = ti + (L - FT(ti));
    const bool diag = (ti == tj);

    __shared__ __bf16 As[128 * 64];   // 16 KB, row stride 64 bf16, XOR-swizzled chunks
    __shared__ __bf16 Bs[128 * 64];
    __shared__ float2 metaS[256];     // [0,128) rows, [128,256) cols
    __shared__ float  red[4];

    const int tid  = threadIdx.x;
    const int lane = tid & 63;
    const int wid  = tid >> 6;
    const int wm   = wid >> 1;        // 0..1
    const int wn   = wid & 1;         // 0..1
    const int quad = lane >> 4;
    const int coll = lane & 15;
    const int rowq = quad * 4;

    const int i0 = ti * 128;
    const int j0 = tj * 128;

    if (tid < 128) metaS[tid] = meta[i0 + tid];
    else           metaS[tid] = meta[j0 + tid - 128];

    f32x4 acc[4][4];
    #pragma unroll
    for (int a = 0; a < 4; a++)
        #pragma unroll
        for (int b = 0; b < 4; b++)
            acc[a][b] = (f32x4){0.f, 0.f, 0.f, 0.f};

    for (int k0 = 0; k0 < DDIM; k0 += 64) {
        // DMA stage: 1024 slots of 16 B per tile. LDS slot s holds global
        // chunk ((s&7) ^ ((s>>3)&7)) of row (s>>3)  -> conflict-free ds_read.
        #pragma unroll
        for (int it = 0; it < 4; ++it) {
            const int slotbase = it * 256 + wid * 64;        // wave-uniform
            const int slot = slotbase + lane;
            const int row  = slot >> 3;
            const int cg   = (slot & 7) ^ (row & 7);
            gload_lds16(Fb + (size_t)(i0 + row) * DDIM + k0 + cg * 8, &As[slotbase * 8]);
            gload_lds16(Fb + (size_t)(j0 + row) * DDIM + k0 + cg * 8, &Bs[slotbase * 8]);
        }
        __syncthreads();

        #pragma unroll
        for (int ks = 0; ks < 2; ++ks) {
            const int perm  = ((ks * 4 + quad) ^ (lane & 7)) * 8;
            const int abase = (wm * 64 + coll) * 64 + perm;
            const int bbase = (wn * 64 + coll) * 64 + perm;
            bf16x8 af[4], bg[4];
            #pragma unroll
            for (int t = 0; t < 4; t++) {
                af[t] = *reinterpret_cast<const bf16x8*>(&As[abase + t * 1024]);
                bg[t] = *reinterpret_cast<const bf16x8*>(&Bs[bbase + t * 1024]);
            }
            #pragma unroll
            for (int tm = 0; tm < 4; tm++)
                #pragma unroll
                for (int tn = 0; tn < 4; tn++)
                    acc[tm][tn] = __builtin_amdgcn_mfma_f32_16x16x32_bf16(
                        af[tm], bg[tn], acc[tm][tn], 0, 0, 0);
        }
        __syncthreads();
    }

    // Epilogue. C/D layout: col = lane&15, row = quad*4 + reg.
    // Off-diag tiles: every element has i<j. Diag tiles: sum whole tile / 2
    // (i==j gives dist 0 after clamp; (i,j)/(j,i) symmetric).
    float sj[4]; int cj[4];
    #pragma unroll
    for (int tn = 0; tn < 4; tn++) {
        float2 mm = metaS[128 + wn * 64 + tn * 16 + coll];
        sj[tn] = mm.x; cj[tn] = __float_as_int(mm.y);
    }

    float lsum = 0.0f, dmin = 1e30f;
    #pragma unroll
    for (int tm = 0; tm < 4; tm++) {
        #pragma unroll
        for (int r = 0; r < 4; r++) {
            float2 mr = metaS[wm * 64 + tm * 16 + rowq + r];
            const float si = mr.x;
            const int   ci = __float_as_int(mr.y);
            #pragma unroll
            for (int tn = 0; tn < 4; tn++) {
                float d2   = fmaxf(fmaf(acc[tm][tn][r], -2.0f, si + sj[tn]), 0.0f);
                float dist = __builtin_amdgcn_sqrtf(d2);
                bool  same = (((ci ^ cj[tn]) >> 1) == 0);
                lsum += same ? dist : 0.0f;
                dmin  = fminf(dmin, d2);
            }
        }
    }

    // Exact margin terms — only possible when some d2 < MARGIN2^2.
    // (Always fires on diagonal tiles via d2_ii = 0; adds nothing there.)
    if (__any(dmin < MARGIN2 * MARGIN2)) {
        #pragma unroll
        for (int tm = 0; tm < 4; tm++) {
            #pragma unroll
            for (int r = 0; r < 4; r++) {
                float2 mr = metaS[wm * 64 + tm * 16 + rowq + r];
                const float si = mr.x;
                const int   ci = __float_as_int(mr.y);
                #pragma unroll
                for (int tn = 0; tn < 4; tn++) {
                    int x = ci ^ cj[tn];
                    if ((x >> 1) != 0) {
                        float d2   = fmaxf(fmaf(acc[tm][tn][r], -2.0f, si + sj[tn]), 0.0f);
                        float dist = __builtin_amdgcn_sqrtf(d2);
                        float m    = (x & 1) ? MARGIN2 : MARGIN1;
                        lsum += fmaxf(m - dist, 0.0f);
                    }
                }
            }
        }
    }

    #pragma unroll
    for (int off = 32; off > 0; off >>= 1) lsum += __shfl_xor(lsum, off, 64);
    if (lane == 0) red[wid] = lsum;
    __syncthreads();
    if (tid == 0)
        partial[L] = (red[0] + red[1] + red[2] + red[3]) * (diag ? 0.5f : 1.0f);
}

__global__ __launch_bounds__(256) void reduce_kernel(
    const float* __restrict__ partial, float* __restrict__ out)
{
    __shared__ float red[4];
    float s = 0.0f;
    for (int i = threadIdx.x; i < NBLK; i += 256) s += partial[i];
    #pragma unroll
    for (int off = 32; off > 0; off >>= 1) s += __shfl_xor(s, off, 64);
    const int lane = threadIdx.x & 63, wid = threadIdx.x >> 6;
    if (lane == 0) red[wid] = s;
    __syncthreads();
    if (threadIdx.x == 0)
        out[0] = (red[0] + red[1] + red[2] + red[3]) * INV_NPAIRS;
}

extern "C" void kernel_launch(void* const* d_in, const int* in_sizes, int n_in,
                              void* d_out, int out_size, void* d_ws, size_t ws_size,
                              hipStream_t stream) {
    const float* F       = (const float*)d_in[0];
    const int*   labels  = (const int*)d_in[1];
    const int*   mlabels = (const int*)d_in[2];
    float*       out     = (float*)d_out;

    __bf16* Fb      = (__bf16*)d_ws;                                   // 4 MiB
    float2* meta    = (float2*)((char*)d_ws + (size_t)BDIM * DDIM * 2); // 64 KiB
    float*  partial = (float*)((char*)meta + (size_t)BDIM * sizeof(float2));

    prep_kernel<<<BDIM / 4, 256, 0, stream>>>(F, labels, mlabels, Fb, meta);
    pair_loss_kernel<<<NBLK, 256, 0, stream>>>(Fb, meta, partial);
    reduce_kernel<<<1, 256, 0, stream>>>(partial, out);
}